// Round 1
// baseline (179.062 us; speedup 1.0000x reference)
//
#include <hip/hip_runtime.h>

// Problem constants (match reference)
#define NX_ 64
#define NY_ 64
#define NBINS 128
#define NSUB 10
#define NV (NSUB * NBINS)      // 1280
#define PADL NV                // 1280
#define ROWLEN (NV + 2 * PADL) // 3840
#define BATCH 32
#define CELLS (BATCH * NY_ * NX_)  // 131072

// Setup: v_idx depends only on (b, k). Compute 32*128 indices into d_ws.
// Must bit-match: xlin = linspace(0, V_RANGE, 128) in f32 (endpoint forced),
// v_samp = -dv + xlin, v_idx = PAD + trunc(v_samp / V_BASE_RES).
__global__ void vidx_setup_kernel(const float* __restrict__ deltas,
                                  int* __restrict__ tab,
                                  float vr_f, float vbase_f) {
    int i = blockIdx.x * blockDim.x + threadIdx.x;
    if (i >= BATCH * NBINS) return;
    int b = i >> 7;
    int k = i & (NBINS - 1);
    float dv = deltas[b * 3 + 2];
    float step = vr_f / 127.0f;                      // f32, as XLA linspace computes delta
    float xl = (k == NBINS - 1) ? vr_f : (float)k * step;  // endpoint fixup (numpy parity)
    float vs = -dv + xl;
    tab[i] = PADL + (int)(vs / vbase_f);             // IEEE f32 div, trunc toward zero
}

// Main gather: 8 cells per 256-thread block, 32 lanes/cell, 4 k per lane.
__global__ __launch_bounds__(256) void gather_kernel(
    const float* __restrict__ cur_pos,   // (B,64,64,2)
    const float* __restrict__ deltas,    // (B,3)
    const float* __restrict__ voxel,     // (64,64,3840)
    const int* __restrict__ is_cam,      // scalar
    const int* __restrict__ tab,         // (B,128) precomputed v_idx
    float* __restrict__ out)             // (B,64,64,128)
{
    int cell = blockIdx.x * 8 + (threadIdx.x >> 5);
    int lane = threadIdx.x & 31;
    int b = cell >> 12;  // 4096 cells per batch

    float sign = (is_cam[0] != 0) ? 1.0f : -1.0f;
    float2 p = ((const float2*)cur_pos)[cell];
    float dx = deltas[b * 3 + 0];
    float dy = deltas[b * 3 + 1];

    // clamp(pos + sign*d, -1, 1); idx = trunc(32*(samp+1)); clamp 0..63
    float xs = fminf(fmaxf(p.x + sign * dx, -1.0f), 1.0f);
    float ys = fminf(fmaxf(p.y + sign * dy, -1.0f), 1.0f);
    int xi = (int)(32.0f * (xs + 1.0f));
    int yi = (int)(32.0f * (ys + 1.0f));
    xi = min(max(xi, 0), NX_ - 1);
    yi = min(max(yi, 0), NY_ - 1);

    const float* __restrict__ row = voxel + (size_t)(yi * NX_ + xi) * ROWLEN;
    const int* __restrict__ t = tab + b * NBINS + lane * 4;

    int i0 = t[0], i1 = t[1], i2 = t[2], i3 = t[3];
    float4 r;
    r.x = row[i0];
    r.y = row[i1];
    r.z = row[i2];
    r.w = row[i3];
    ((float4*)out)[(size_t)cell * 32 + lane] = r;
}

extern "C" void kernel_launch(void* const* d_in, const int* in_sizes, int n_in,
                              void* d_out, int out_size, void* d_ws, size_t ws_size,
                              hipStream_t stream) {
    const float* cur_pos = (const float*)d_in[0];
    const float* deltas  = (const float*)d_in[1];
    const float* voxel   = (const float*)d_in[2];
    const int*   is_cam  = (const int*)d_in[3];
    float* out = (float*)d_out;
    int* tab = (int*)d_ws;  // 32*128 ints = 16 KB

    // Constants derived in f64 exactly as the Python module level does, then narrowed.
    const double vr_d = ((3.0e8 * 128.0) * 32e-12 / 2.0) * ((3.0e8 * 128.0) * 32e-12 / 2.0);
    const float vr_f = (float)vr_d;
    const float vbase_f = (float)(vr_d / (double)NV);

    hipLaunchKernelGGL(vidx_setup_kernel, dim3((BATCH * NBINS + 255) / 256), dim3(256),
                       0, stream, deltas, tab, vr_f, vbase_f);

    hipLaunchKernelGGL(gather_kernel, dim3(CELLS / 8), dim3(256), 0, stream,
                       cur_pos, deltas, voxel, is_cam, tab, out);
}

// Round 5
// 135.450 us; speedup vs baseline: 1.3220x; 1.3220x over previous
//
#include <hip/hip_runtime.h>

// Problem constants (match reference)
#define NX_ 64
#define NY_ 64
#define NBINS 128
#define NSUB 10
#define NV (NSUB * NBINS)      // 1280
#define PADL NV                // 1280
#define ROWLEN (NV + 2 * PADL) // 3840
#define BATCH 32
#define NROWS (NY_ * NX_)          // 4096
#define CELLS (BATCH * NY_ * NX_)  // 131072
#define CAP 128                    // bucket capacity per row (avg occupancy ~39)

// Pass 1: v_idx depends only on (b, k) -> 32*128 table. Also zero row counters.
// Bit-parity: xlin = f32 linspace(0, V_RANGE, 128) w/ endpoint fixup,
// v_idx = PAD + trunc((-dv + xlin) / V_BASE_RES), IEEE f32 div, trunc toward 0.
__global__ __launch_bounds__(256) void vidx_setup_kernel(
    const float* __restrict__ deltas, int* __restrict__ tab,
    int* __restrict__ cnt, float vr_f, float vbase_f) {
    int i = blockIdx.x * blockDim.x + threadIdx.x;
    if (i >= BATCH * NBINS) return;
    if (i < NROWS) cnt[i] = 0;
    int b = i >> 7;
    int k = i & (NBINS - 1);
    float dv = deltas[b * 3 + 2];
    float step = vr_f / 127.0f;
    float xl = (k == NBINS - 1) ? vr_f : (float)k * step;
    float vs = -dv + xl;
    tab[i] = PADL + (int)(vs / vbase_f);
}

// Pass 2: bin each cell by its (yi, xi) table row. Overflow (never expected:
// avg 39/row, CAP 128) falls back to a direct global gather for correctness.
__global__ __launch_bounds__(256) void bin_kernel(
    const float* __restrict__ cur_pos,   // (B,64,64,2)
    const float* __restrict__ deltas,    // (B,3)
    const int* __restrict__ is_cam,
    const float* __restrict__ voxel,     // for overflow slow path
    const int* __restrict__ tab,
    int* __restrict__ cnt,               // (4096) zeroed by pass 1
    unsigned* __restrict__ bucket,       // (4096, CAP)
    float* __restrict__ out)
{
    int cell = blockIdx.x * 256 + threadIdx.x;
    int b = cell >> 12;  // 4096 cells per batch

    float sign = (is_cam[0] != 0) ? 1.0f : -1.0f;
    float2 p = ((const float2*)cur_pos)[cell];
    float dx = deltas[b * 3 + 0];
    float dy = deltas[b * 3 + 1];

    float xs = fminf(fmaxf(p.x + sign * dx, -1.0f), 1.0f);
    float ys = fminf(fmaxf(p.y + sign * dy, -1.0f), 1.0f);
    int xi = (int)(32.0f * (xs + 1.0f));
    int yi = (int)(32.0f * (ys + 1.0f));
    xi = min(max(xi, 0), NX_ - 1);
    yi = min(max(yi, 0), NY_ - 1);
    int r = yi * NX_ + xi;

    int pos = atomicAdd(&cnt[r], 1);
    if (pos < CAP) {
        bucket[r * CAP + pos] = (unsigned)cell;
    } else {
        // slow path: serve this cell directly from global (correctness net)
        const float* __restrict__ row = voxel + (size_t)r * ROWLEN;
        const int* __restrict__ t = tab + b * NBINS;
        float* __restrict__ o = out + (size_t)cell * NBINS;
        for (int k = 0; k < NBINS; ++k) o[k] = row[t[k]];
    }
}

// Pass 3: one block per table row. Stage the union span [lo..hi] into LDS once,
// then serve every cell binned to this row from LDS. 8 cells in flight
// (32 lanes/cell; lane handles k = lane + 32j -> LDS index stride ~10 floats
// across lanes => ~4-way bank aliasing, near-free; stores stride-1 coalesced).
__global__ __launch_bounds__(256) void row_gather_kernel(
    const float* __restrict__ voxel,     // (64,64,3840)
    const int* __restrict__ tab,         // (B,128)
    const int* __restrict__ cnt,         // (4096)
    const unsigned* __restrict__ bucket, // (4096, CAP)
    float* __restrict__ out)             // (B,64,64,128)
{
    int r = blockIdx.x;
    int n = cnt[r];
    if (n == 0) return;
    if (n > CAP) n = CAP;

    __shared__ float span[ROWLEN];   // worst-case full row, 15 KB
    __shared__ int s_lo, s_len;

    int tid = threadIdx.x;

    // lo = min_b tab[b][0], hi = max_b tab[b][127]  (tab monotone in k).
    if (tid < 64) {
        int bb = tid & 31;
        int lo = tab[bb * 128];
        int hi = tab[bb * 128 + 127];
        #pragma unroll
        for (int m = 16; m >= 1; m >>= 1) {
            lo = min(lo, __shfl_xor(lo, m));
            hi = max(hi, __shfl_xor(hi, m));
        }
        if (tid == 0) {
            lo = max(lo, 0);
            hi = min(hi, ROWLEN - 1);
            s_lo = lo;
            s_len = hi - lo + 1;
        }
    }
    __syncthreads();

    int lo = s_lo, len = s_len;
    const float* __restrict__ row = voxel + (size_t)r * ROWLEN;
    for (int i = tid; i < len; i += 256) span[i] = row[lo + i];
    __syncthreads();

    int g = tid >> 5, lane = tid & 31;
    for (int ci = g; ci < n; ci += 8) {
        unsigned cell = bucket[r * CAP + ci];
        int b = (int)(cell >> 12);
        const int* __restrict__ t = tab + b * NBINS;
        int i0 = t[lane]      - lo;
        int i1 = t[lane + 32] - lo;
        int i2 = t[lane + 64] - lo;
        int i3 = t[lane + 96] - lo;
        float v0 = span[i0], v1 = span[i1], v2 = span[i2], v3 = span[i3];
        float* __restrict__ o = out + (size_t)cell * NBINS;
        o[lane]      = v0;
        o[lane + 32] = v1;
        o[lane + 64] = v2;
        o[lane + 96] = v3;
    }
}

extern "C" void kernel_launch(void* const* d_in, const int* in_sizes, int n_in,
                              void* d_out, int out_size, void* d_ws, size_t ws_size,
                              hipStream_t stream) {
    const float* cur_pos = (const float*)d_in[0];
    const float* deltas  = (const float*)d_in[1];
    const float* voxel   = (const float*)d_in[2];
    const int*   is_cam  = (const int*)d_in[3];
    float* out = (float*)d_out;

    // d_ws layout: tab (16 KB) | cnt (16 KB) | bucket (2 MB)
    int* tab = (int*)d_ws;
    int* cnt = tab + BATCH * NBINS;
    unsigned* bucket = (unsigned*)(cnt + NROWS);

    const double vr_d = ((3.0e8 * 128.0) * 32e-12 / 2.0) * ((3.0e8 * 128.0) * 32e-12 / 2.0);
    const float vr_f = (float)vr_d;
    const float vbase_f = (float)(vr_d / (double)NV);

    hipLaunchKernelGGL(vidx_setup_kernel, dim3((BATCH * NBINS + 255) / 256), dim3(256),
                       0, stream, deltas, tab, cnt, vr_f, vbase_f);

    hipLaunchKernelGGL(bin_kernel, dim3(CELLS / 256), dim3(256), 0, stream,
                       cur_pos, deltas, is_cam, voxel, tab, cnt, bucket, out);

    hipLaunchKernelGGL(row_gather_kernel, dim3(NROWS), dim3(256), 0, stream,
                       voxel, tab, cnt, bucket, out);
}

// Round 6
// 134.193 us; speedup vs baseline: 1.3344x; 1.0094x over previous
//
#include <hip/hip_runtime.h>

// Problem constants (match reference)
#define NX_ 64
#define NY_ 64
#define NBINS 128
#define NSUB 10
#define NV (NSUB * NBINS)      // 1280
#define PADL NV                // 1280
#define ROWLEN (NV + 2 * PADL) // 3840
#define BATCH 32
#define NROWS (NY_ * NX_)          // 4096
#define CELLS (BATCH * NY_ * NX_)  // 131072
#define CAP 128                    // bucket capacity per row (avg occupancy ~39, max ~77)

// Pass 1: v_idx depends only on (b, k) -> 32*128 table. Also zero row counters.
// Bit-parity: xlin = f32 linspace(0, V_RANGE, 128) w/ endpoint fixup,
// v_idx = PAD + trunc((-dv + xlin) / V_BASE_RES), IEEE f32 div, trunc toward 0.
__global__ __launch_bounds__(256) void vidx_setup_kernel(
    const float* __restrict__ deltas, int* __restrict__ tab,
    int* __restrict__ cnt, float vr_f, float vbase_f) {
    int i = blockIdx.x * blockDim.x + threadIdx.x;
    if (i >= BATCH * NBINS) return;
    if (i < NROWS) cnt[i] = 0;
    int b = i >> 7;
    int k = i & (NBINS - 1);
    float dv = deltas[b * 3 + 2];
    float step = vr_f / 127.0f;
    float xl = (k == NBINS - 1) ? vr_f : (float)k * step;
    float vs = -dv + xl;
    tab[i] = PADL + (int)(vs / vbase_f);
}

// Pass 2: bin each cell by its (yi, xi) table row. Overflow (never expected:
// avg 39/row, CAP 128) falls back to a direct global gather for correctness.
__global__ __launch_bounds__(256) void bin_kernel(
    const float* __restrict__ cur_pos,   // (B,64,64,2)
    const float* __restrict__ deltas,    // (B,3)
    const int* __restrict__ is_cam,
    const float* __restrict__ voxel,     // for overflow slow path
    const int* __restrict__ tab,
    int* __restrict__ cnt,               // (4096) zeroed by pass 1
    unsigned* __restrict__ bucket,       // (4096, CAP)
    float* __restrict__ out)
{
    int cell = blockIdx.x * 256 + threadIdx.x;
    int b = cell >> 12;  // 4096 cells per batch

    float sign = (is_cam[0] != 0) ? 1.0f : -1.0f;
    float2 p = ((const float2*)cur_pos)[cell];
    float dx = deltas[b * 3 + 0];
    float dy = deltas[b * 3 + 1];

    float xs = fminf(fmaxf(p.x + sign * dx, -1.0f), 1.0f);
    float ys = fminf(fmaxf(p.y + sign * dy, -1.0f), 1.0f);
    int xi = (int)(32.0f * (xs + 1.0f));
    int yi = (int)(32.0f * (ys + 1.0f));
    xi = min(max(xi, 0), NX_ - 1);
    yi = min(max(yi, 0), NY_ - 1);
    int r = yi * NX_ + xi;

    int pos = atomicAdd(&cnt[r], 1);
    if (pos < CAP) {
        bucket[r * CAP + pos] = (unsigned)cell;
    } else {
        // slow path: serve this cell directly from global (correctness net)
        const float* __restrict__ row = voxel + (size_t)r * ROWLEN;
        const int* __restrict__ t = tab + b * NBINS;
        float* __restrict__ o = out + (size_t)cell * NBINS;
        for (int k = 0; k < NBINS; ++k) o[k] = row[t[k]];
    }
}

// Pass 3: one block per table row. Stage the union span [lo4..end4) into LDS
// once (float4), then serve every cell binned to this row from LDS.
// 512 threads = 16 groups of 32 lanes; lane handles k = lane + 32j -> LDS
// index stride ~10 floats across lanes => ~4-way bank aliasing, near-free;
// stores stride-1 coalesced (128 B per group-instruction).
__global__ __launch_bounds__(512) void row_gather_kernel(
    const float* __restrict__ voxel,     // (64,64,3840)
    const int* __restrict__ tab,         // (B,128)
    const int* __restrict__ cnt,         // (4096)
    const unsigned* __restrict__ bucket, // (4096, CAP)
    float* __restrict__ out)             // (B,64,64,128)
{
    int r = blockIdx.x;
    int n = cnt[r];
    if (n == 0) return;
    if (n > CAP) n = CAP;

    __shared__ __align__(16) float span[ROWLEN];   // worst-case full row, 15 KB
    __shared__ unsigned s_cells[CAP];
    __shared__ int s_lo, s_len;

    int tid = threadIdx.x;

    // stage this row's cell list
    if (tid < n) s_cells[tid] = bucket[r * CAP + tid];

    // lo = min_b tab[b][0], hi = max_b tab[b][127]  (tab monotone in k).
    if (tid < 64) {
        int bb = tid & 31;
        int lo = tab[bb * 128];
        int hi = tab[bb * 128 + 127];
        #pragma unroll
        for (int m = 16; m >= 1; m >>= 1) {
            lo = min(lo, __shfl_xor(lo, m));
            hi = max(hi, __shfl_xor(hi, m));
        }
        if (tid == 0) {
            lo = max(lo, 0);
            hi = min(hi, ROWLEN - 1);
            s_lo = lo;
            s_len = hi - lo + 1;
        }
    }
    __syncthreads();

    // float4 staging of [lo4, end4) — row base is 16B-aligned (ROWLEN%4==0).
    int lo4 = s_lo & ~3;
    int end4 = (s_lo + s_len + 3) & ~3;
    if (end4 > ROWLEN) end4 = ROWLEN;
    int nvec = (end4 - lo4) >> 2;
    const float4* __restrict__ row4 =
        (const float4*)(voxel + (size_t)r * ROWLEN) + (lo4 >> 2);
    float4* span4 = (float4*)span;
    for (int i = tid; i < nvec; i += 512) span4[i] = row4[i];
    __syncthreads();

    int g = tid >> 5, lane = tid & 31;
    for (int ci = g; ci < n; ci += 16) {
        unsigned cell = s_cells[ci];
        int b = (int)(cell >> 12);
        const int* __restrict__ t = tab + b * NBINS;
        int i0 = t[lane]      - lo4;
        int i1 = t[lane + 32] - lo4;
        int i2 = t[lane + 64] - lo4;
        int i3 = t[lane + 96] - lo4;
        float v0 = span[i0], v1 = span[i1], v2 = span[i2], v3 = span[i3];
        float* __restrict__ o = out + (size_t)cell * NBINS;
        o[lane]      = v0;
        o[lane + 32] = v1;
        o[lane + 64] = v2;
        o[lane + 96] = v3;
    }
}

extern "C" void kernel_launch(void* const* d_in, const int* in_sizes, int n_in,
                              void* d_out, int out_size, void* d_ws, size_t ws_size,
                              hipStream_t stream) {
    const float* cur_pos = (const float*)d_in[0];
    const float* deltas  = (const float*)d_in[1];
    const float* voxel   = (const float*)d_in[2];
    const int*   is_cam  = (const int*)d_in[3];
    float* out = (float*)d_out;

    // d_ws layout: tab (16 KB) | cnt (16 KB) | bucket (2 MB)
    int* tab = (int*)d_ws;
    int* cnt = tab + BATCH * NBINS;
    unsigned* bucket = (unsigned*)(cnt + NROWS);

    const double vr_d = ((3.0e8 * 128.0) * 32e-12 / 2.0) * ((3.0e8 * 128.0) * 32e-12 / 2.0);
    const float vr_f = (float)vr_d;
    const float vbase_f = (float)(vr_d / (double)NV);

    hipLaunchKernelGGL(vidx_setup_kernel, dim3((BATCH * NBINS + 255) / 256), dim3(256),
                       0, stream, deltas, tab, cnt, vr_f, vbase_f);

    hipLaunchKernelGGL(bin_kernel, dim3(CELLS / 256), dim3(256), 0, stream,
                       cur_pos, deltas, is_cam, voxel, tab, cnt, bucket, out);

    hipLaunchKernelGGL(row_gather_kernel, dim3(NROWS), dim3(512), 0, stream,
                       voxel, tab, cnt, bucket, out);
}